// Round 8
// baseline (493.090 us; speedup 1.0000x reference)
//
#include <hip/hip_runtime.h>
#include <hip/hip_bf16.h>
#include <math.h>

#define N_TOK 16384
#define D_MODEL 2048
#define N_EXP 64
#define CAPACITY 640
#define KSPLIT 4
#define KSLICE (D_MODEL / KSPLIT)  // 512
#define NREP 8

// ---------------- K0: pack W[e][k] -> Wt4[k4][e][4] -------------------------
// Wt4[((k4)*64 + e)*4 + j] = W[e][4*k4 + j]; writes coalesced, 512 KB total.
__global__ __launch_bounds__(256) void k0_pack(
    const float* __restrict__ W, float* __restrict__ Wt4) {
  const int tid = blockIdx.x * 256 + threadIdx.x;  // 32768 = 512 k4 x 64 e
  const int e = tid & 63;
  const int k4 = tid >> 6;
  const float4 v = *(const float4*)(W + (size_t)e * D_MODEL + 4 * k4);
  *(float4*)(Wt4 + (size_t)tid * 4) = v;  // [k4][e][4], fully coalesced
}

// ---------------- K1: split-K GEMM, lane=expert, x via scalar path ----------
// grid 1024 = 4 kslices x 256 token-groups; block 256 = 4 waves;
// wave: 16 tokens x 64 experts, acc[16]; x wave-uniform -> s_load_dwordx4;
// W: one coalesced float4 per lane per k4 (lane's expert, 4 k's).
__global__ __launch_bounds__(256) void k1_gemm(
    const float* __restrict__ x, const float* __restrict__ Wt4,
    float* __restrict__ part) {
  const int lane = threadIdx.x & 63;
  const int wid = __builtin_amdgcn_readfirstlane(threadIdx.x >> 6);
  const int ks = blockIdx.x >> 8;    // k-slice 0..3
  const int grp = blockIdx.x & 255;  // token group 0..255
  const int n0 = grp * 64 + wid * 16;
  const int kb = ks * KSLICE;

  const float* xr = x + (size_t)n0 * D_MODEL + kb;  // wave-uniform base
  const float4* wp = (const float4*)Wt4 + (size_t)(kb >> 2) * N_EXP + lane;

  float acc[16] = {};

#pragma unroll 2
  for (int k4 = 0; k4 < KSLICE / 4; k4++) {
    const float4 w = wp[(size_t)k4 * N_EXP];
#pragma unroll
    for (int i = 0; i < 16; i++) {
      const float4 xv = *(const float4*)(xr + (size_t)i * D_MODEL + 4 * k4);
      float a = acc[i];
      a = fmaf(xv.x, w.x, a);
      a = fmaf(xv.y, w.y, a);
      a = fmaf(xv.z, w.z, a);
      a = fmaf(xv.w, w.w, a);
      acc[i] = a;
    }
  }

  // part[ks][n][e]: per i, 64 lanes write 256 B contiguous
  float* pp = part + ((size_t)ks * N_TOK + n0) * N_EXP + lane;
#pragma unroll
  for (int i = 0; i < 16; i++) pp[(size_t)i * N_EXP] = acc[i];
}

// ---------------- K2: wave-per-token softmax + top2 + z + hist --------------
__global__ __launch_bounds__(256) void k2_softmax(
    const float* __restrict__ part, float* __restrict__ rw_out,
    int2* __restrict__ top12, float2* __restrict__ wts,
    int* __restrict__ histR, float* __restrict__ zR) {
  __shared__ float zred[4];
  const int lane = threadIdx.x & 63;
  const int wid = threadIdx.x >> 6;
  const int n = blockIdx.x * 4 + wid;
  const int rep = blockIdx.x & (NREP - 1);

  float v = 0.f;
#pragma unroll
  for (int s = 0; s < KSPLIT; s++)
    v += part[((size_t)s * N_TOK + n) * N_EXP + lane];

  float zp = v * v;
#pragma unroll
  for (int off = 32; off; off >>= 1) zp += __shfl_xor(zp, off);

  float m = v;
#pragma unroll
  for (int off = 32; off; off >>= 1) m = fmaxf(m, __shfl_xor(m, off));
  float p = __expf(v - m);
  float ssum = p;
#pragma unroll
  for (int off = 32; off; off >>= 1) ssum += __shfl_xor(ssum, off);
  const float rw = p / ssum;
  rw_out[(size_t)n * N_EXP + lane] = rw;

  const unsigned long long b1 = __ballot(v == m);
  const int i1 = __builtin_ctzll(b1);
  float v2 = (lane == i1) ? -INFINITY : v;
#pragma unroll
  for (int off = 32; off; off >>= 1) v2 = fmaxf(v2, __shfl_xor(v2, off));
  const unsigned long long b2 = __ballot(v == v2) & ~(1ull << i1);
  const int i2 = __builtin_ctzll(b2);

  const float rw1 = __shfl(rw, i1);
  const float rw2 = __shfl(rw, i2);
  if (lane == 0) {
    const float denom = rw1 + rw2 + 1e-8f;
    top12[n] = make_int2(i1, i2);
    wts[n] = make_float2(rw1 / denom, rw2 / denom);
    atomicAdd(&histR[(rep * N_EXP + i1) * 16], 1);
    zred[wid] = zp;
  }
  __syncthreads();
  if (threadIdx.x == 0)
    atomicAdd(&zR[rep * 16], zred[0] + zred[1] + zred[2] + zred[3]);
}

// ---------------- K3: wave-per-token dispatch mask + counts -----------------
__global__ __launch_bounds__(256) void k3_dispatch(
    const int2* __restrict__ top12, const float2* __restrict__ wts,
    const int* __restrict__ histR, float* __restrict__ mask_out,
    float* __restrict__ cntR) {
  const int lane = threadIdx.x & 63;
  const int wid = threadIdx.x >> 6;
  const int n = blockIdx.x * 4 + wid;
  const int rep = blockIdx.x & (NREP - 1);

  const int2 ij = top12[n];
  const float2 w = wts[n];
  int h = 0;
#pragma unroll
  for (int r = 0; r < NREP; r++) h += histR[(r * N_EXP + ij.y) * 16];
  const bool allowed = h < CAPACITY;
  const float ssum = w.x + (allowed ? w.y : 0.f);
  const float inv = 1.f / (ssum + 1e-8f);
  float val = 0.f;
  if (lane == ij.x) val = w.x * inv;
  else if (allowed && lane == ij.y) val = w.y * inv;
  mask_out[(size_t)n * N_EXP + lane] = val;
  if (val != 0.f) atomicAdd(&cntR[(rep * N_EXP + lane) * 16], val);
}

// ---------------- K4: scalar loss -------------------------------------------
__global__ void k4_loss(const float* __restrict__ cntR,
                        const float* __restrict__ zR,
                        float* __restrict__ loss_out) {
  const int lane = threadIdx.x;
  float c = 0.f;
#pragma unroll
  for (int r = 0; r < NREP; r++) c += cntR[(r * N_EXP + lane) * 16];
  const float d = (c - 512.0f) * (1.0f / 16384.0f);
  float v = d * d;
#pragma unroll
  for (int off = 32; off; off >>= 1) v += __shfl_xor(v, off);
  if (lane == 0) {
    float z = 0.f;
#pragma unroll
    for (int r = 0; r < NREP; r++) z += zR[r * 16];
    const float lb = v * (1.0f / 64.0f);
    loss_out[0] = 0.001f * (z * (1.0f / (16384.0f * 64.0f))) + 0.001f * lb;
  }
}

extern "C" void kernel_launch(void* const* d_in, const int* in_sizes, int n_in,
                              void* d_out, int out_size, void* d_ws, size_t ws_size,
                              hipStream_t stream) {
  const float* x = (const float*)d_in[0];
  const float* W = (const float*)d_in[1];
  float* out = (float*)d_out;
  float* rw_out = out;
  float* mask_out = out + (size_t)N_TOK * N_EXP;
  float* loss_out = out + 2 * (size_t)N_TOK * N_EXP;

  char* ws = (char*)d_ws;
  float* part = (float*)ws;                        // 4 x 16384 x 64 x 4B = 16 MB
  float* Wt4 = (float*)(ws + 16777216);            // 512 KB
  int* histR = (int*)(ws + 17301504);              // 32 KB (8 reps x 64 x s16)
  float* cntR = (float*)(ws + 17301504 + 32768);   // 32 KB
  float* zR = (float*)(ws + 17301504 + 65536);     // 512 B
  int2* top12 = (int2*)(ws + 17301504 + 131072);   // 128 KB
  float2* wts = (float2*)(ws + 17301504 + 262144); // 128 KB

  hipMemsetAsync(histR, 0, 65536 + 512, stream);
  k0_pack<<<128, 256, 0, stream>>>(W, Wt4);
  k1_gemm<<<KSPLIT * 256, 256, 0, stream>>>(x, Wt4, part);
  k2_softmax<<<N_TOK / 4, 256, 0, stream>>>(part, rw_out, top12, wts, histR, zR);
  k3_dispatch<<<N_TOK / 4, 256, 0, stream>>>(top12, wts, histR, mask_out, cntR);
  k4_loss<<<1, 64, 0, stream>>>(cntR, zR, loss_out);
}